// Round 1
// baseline (229.140 us; speedup 1.0000x reference)
//
#include <hip/hip_runtime.h>

// Problem constants (from reference): T=16, H=1280, W=1280, N=64 boxes.
#define TT 16
#define HH 1280
#define WW 1280
#define NBOX 64

// Kernel 1: build row/col membership bitmasks (one bit per box) and zero d_out.
// rowmask[y] bit b set iff y1_b <= y < y2_b ; colmask[x] bit b set iff x1_b <= x < x2_b.
// Box layout per reference: boxes[b] = (x1, y1, x2, y2), half-open [lo, hi).
__global__ void build_masks_kernel(const int* __restrict__ boxes,
                                   unsigned long long* __restrict__ rowmask,
                                   unsigned long long* __restrict__ colmask,
                                   float* __restrict__ out) {
    __shared__ int bx1[NBOX], by1[NBOX], bx2[NBOX], by2[NBOX];
    int tid = threadIdx.x;
    if (tid < NBOX) {
        bx1[tid] = boxes[tid * 4 + 0];
        by1[tid] = boxes[tid * 4 + 1];
        bx2[tid] = boxes[tid * 4 + 2];
        by2[tid] = boxes[tid * 4 + 3];
    }
    if (tid == 0) out[0] = 0.0f;
    __syncthreads();
    // H == W, so one loop builds both masks.
    for (int i = tid; i < HH; i += blockDim.x) {
        unsigned long long rm = 0ull, cm = 0ull;
#pragma unroll
        for (int b = 0; b < NBOX; ++b) {
            if (by1[b] <= i && i < by2[b]) rm |= (1ull << b);
            if (bx1[b] <= i && i < bx2[b]) cm |= (1ull << b);
        }
        rowmask[i] = rm;
        colmask[i] = cm;
    }
}

// Kernel 2: weighted full reduction. weight(y,x) = popcount(rowmask[y] & colmask[x]).
__global__ void __launch_bounds__(256)
weighted_sum_kernel(const float4* __restrict__ data,
                    const unsigned long long* __restrict__ rowmask,
                    const unsigned long long* __restrict__ colmask,
                    float* __restrict__ out) {
    const int W4 = WW / 4;            // 320 float4 per row
    const int n4 = TT * HH * W4;      // total float4 count
    const int slice4 = HH * W4;       // float4 per T-slice

    float acc = 0.0f;
    int stride = gridDim.x * blockDim.x;
    for (int i = blockIdx.x * blockDim.x + threadIdx.x; i < n4; i += stride) {
        float4 v = data[i];
        int xy = i % slice4;          // magic-mul, cheap
        int x4 = xy % W4;
        int y  = xy / W4;
        unsigned long long rm = rowmask[y];
        int x = x4 * 4;
        float w0 = (float)__popcll(rm & colmask[x + 0]);
        float w1 = (float)__popcll(rm & colmask[x + 1]);
        float w2 = (float)__popcll(rm & colmask[x + 2]);
        float w3 = (float)__popcll(rm & colmask[x + 3]);
        acc += v.x * w0 + v.y * w1 + v.z * w2 + v.w * w3;
    }

    // Wave (64-lane) shuffle reduction
#pragma unroll
    for (int off = 32; off > 0; off >>= 1)
        acc += __shfl_down(acc, off, 64);

    __shared__ float wsum[4];
    int lane = threadIdx.x & 63;
    int wid  = threadIdx.x >> 6;
    if (lane == 0) wsum[wid] = acc;
    __syncthreads();
    if (threadIdx.x == 0) {
        float s = wsum[0] + wsum[1] + wsum[2] + wsum[3];
        atomicAdd(out, s);
    }
}

extern "C" void kernel_launch(void* const* d_in, const int* in_sizes, int n_in,
                              void* d_out, int out_size, void* d_ws, size_t ws_size,
                              hipStream_t stream) {
    const float* data = (const float*)d_in[0];        // (T,H,W) float32
    const int* boxes  = (const int*)d_in[1];          // (N,4) int32
    float* out = (float*)d_out;                       // scalar

    // Workspace layout: rowmask[HH], colmask[WW] as u64.
    unsigned long long* rowmask = (unsigned long long*)d_ws;
    unsigned long long* colmask = rowmask + HH;

    build_masks_kernel<<<1, 256, 0, stream>>>(boxes, rowmask, colmask, out);

    const int blocks = 4096;
    weighted_sum_kernel<<<blocks, 256, 0, stream>>>(
        (const float4*)data, rowmask, colmask, out);
}

// Round 2
// 205.687 us; speedup vs baseline: 1.1140x; 1.1140x over previous
//
#include <hip/hip_runtime.h>

// Problem constants: T=16, H=1280, W=1280, N=64 boxes.
#define TT 16
#define HH 1280
#define WW 1280
#define NBOX 64
#define W4 (WW / 4)            // 320 float4 per row
#define SITES (HH * W4)        // 409600 (y, x4) sites
#define SLICE4 SITES           // float4 per T-slice

// K1: build row/col membership bitmasks (one bit per box); zero d_out.
// boxes[b] = (x1, y1, x2, y2), half-open [lo, hi).
__global__ void build_masks_kernel(const int* __restrict__ boxes,
                                   unsigned long long* __restrict__ rowmask,
                                   unsigned long long* __restrict__ colmask,
                                   float* __restrict__ out) {
    __shared__ int bx1[NBOX], by1[NBOX], bx2[NBOX], by2[NBOX];
    int tid = threadIdx.x;
    if (tid < NBOX) {
        bx1[tid] = boxes[tid * 4 + 0];
        by1[tid] = boxes[tid * 4 + 1];
        bx2[tid] = boxes[tid * 4 + 2];
        by2[tid] = boxes[tid * 4 + 3];
    }
    if (tid == 0) out[0] = 0.0f;
    __syncthreads();
    for (int i = tid; i < HH; i += blockDim.x) {   // H == W
        unsigned long long rm = 0ull, cm = 0ull;
#pragma unroll
        for (int b = 0; b < NBOX; ++b) {
            if (by1[b] <= i && i < by2[b]) rm |= (1ull << b);
            if (bx1[b] <= i && i < bx2[b]) cm |= (1ull << b);
        }
        rowmask[i] = rm;
        colmask[i] = cm;
    }
}

// K2: build per-pixel weight map as uchar4 per (y, x4) site. Runs once, tiny.
__global__ void __launch_bounds__(256)
build_wmap_kernel(const unsigned long long* __restrict__ rowmask,
                  const unsigned long long* __restrict__ colmask,
                  uchar4* __restrict__ wmap) {
    int idx = blockIdx.x * 256 + threadIdx.x;     // exactly SITES threads
    int y  = idx / W4;
    int x4 = idx % W4;
    unsigned long long rm = rowmask[y];
    int x = x4 * 4;
    uchar4 w;
    w.x = (unsigned char)__popcll(rm & colmask[x + 0]);
    w.y = (unsigned char)__popcll(rm & colmask[x + 1]);
    w.z = (unsigned char)__popcll(rm & colmask[x + 2]);
    w.w = (unsigned char)__popcll(rm & colmask[x + 3]);
    wmap[idx] = w;
}

// K3: each thread owns one (y, x4) site across all T slices.
// One uchar4 weight load per 16 float4 data loads (all coalesced).
__global__ void __launch_bounds__(256)
weighted_sum_kernel(const float4* __restrict__ data,
                    const uchar4* __restrict__ wmap,
                    float* __restrict__ out) {
    int idx = blockIdx.x * 256 + threadIdx.x;     // exactly SITES threads

    uchar4 wb = wmap[idx];
    float w0 = (float)wb.x, w1 = (float)wb.y, w2 = (float)wb.z, w3 = (float)wb.w;

    const float4* p = data + idx;
    float a0 = 0.f, a1 = 0.f, a2 = 0.f, a3 = 0.f;
#pragma unroll
    for (int t = 0; t < TT; t += 4) {
        float4 v0 = p[(t + 0) * SLICE4];
        float4 v1 = p[(t + 1) * SLICE4];
        float4 v2 = p[(t + 2) * SLICE4];
        float4 v3 = p[(t + 3) * SLICE4];
        a0 += v0.x * w0 + v0.y * w1 + v0.z * w2 + v0.w * w3;
        a1 += v1.x * w0 + v1.y * w1 + v1.z * w2 + v1.w * w3;
        a2 += v2.x * w0 + v2.y * w1 + v2.z * w2 + v2.w * w3;
        a3 += v3.x * w0 + v3.y * w1 + v3.z * w2 + v3.w * w3;
    }
    float acc = (a0 + a1) + (a2 + a3);

    // 64-lane wave shuffle reduction
#pragma unroll
    for (int off = 32; off > 0; off >>= 1)
        acc += __shfl_down(acc, off, 64);

    __shared__ float wsum[4];
    int lane = threadIdx.x & 63;
    int wid  = threadIdx.x >> 6;
    if (lane == 0) wsum[wid] = acc;
    __syncthreads();
    if (threadIdx.x == 0) {
        float s = (wsum[0] + wsum[1]) + (wsum[2] + wsum[3]);
        atomicAdd(out, s);
    }
}

extern "C" void kernel_launch(void* const* d_in, const int* in_sizes, int n_in,
                              void* d_out, int out_size, void* d_ws, size_t ws_size,
                              hipStream_t stream) {
    const float* data = (const float*)d_in[0];        // (T,H,W) float32
    const int* boxes  = (const int*)d_in[1];          // (N,4) int32
    float* out = (float*)d_out;                       // scalar

    // Workspace: rowmask[HH] u64, colmask[WW] u64, wmap[SITES] uchar4.
    unsigned long long* rowmask = (unsigned long long*)d_ws;
    unsigned long long* colmask = rowmask + HH;
    uchar4* wmap = (uchar4*)(colmask + WW);

    build_masks_kernel<<<1, 256, 0, stream>>>(boxes, rowmask, colmask, out);
    build_wmap_kernel<<<SITES / 256, 256, 0, stream>>>(rowmask, colmask, wmap);
    weighted_sum_kernel<<<SITES / 256, 256, 0, stream>>>(
        (const float4*)data, wmap, out);
}

// Round 3
// 202.849 us; speedup vs baseline: 1.1296x; 1.0140x over previous
//
#include <hip/hip_runtime.h>

// Problem constants: T=16, H=1280, W=1280, N=64 boxes.
#define TT 16
#define HH 1280
#define WW 1280
#define NBOX 64
#define W4 (WW / 4)            // 320 float4 per row
#define SITES (HH * W4)        // 409600 (y, x4) sites
#define SLICE4 SITES           // float4 per T-slice

// K1: build row/col membership bitmasks (one bit per box); zero d_out.
// boxes[b] = (x1, y1, x2, y2), half-open [lo, hi).
__global__ void build_masks_kernel(const int* __restrict__ boxes,
                                   unsigned long long* __restrict__ rowmask,
                                   unsigned long long* __restrict__ colmask,
                                   float* __restrict__ out) {
    __shared__ int bx1[NBOX], by1[NBOX], bx2[NBOX], by2[NBOX];
    int tid = threadIdx.x;
    if (tid < NBOX) {
        bx1[tid] = boxes[tid * 4 + 0];
        by1[tid] = boxes[tid * 4 + 1];
        bx2[tid] = boxes[tid * 4 + 2];
        by2[tid] = boxes[tid * 4 + 3];
    }
    if (tid == 0) out[0] = 0.0f;
    __syncthreads();
    for (int i = tid; i < HH; i += blockDim.x) {   // H == W
        unsigned long long rm = 0ull, cm = 0ull;
#pragma unroll
        for (int b = 0; b < NBOX; ++b) {
            if (by1[b] <= i && i < by2[b]) rm |= (1ull << b);
            if (bx1[b] <= i && i < bx2[b]) cm |= (1ull << b);
        }
        rowmask[i] = rm;
        colmask[i] = cm;
    }
}

// K2: each thread owns one (y, x4) site across all T=16 slices.
// Weights computed inline (rowmask & colmask popcount), amortized over 16 KB
// of wave data. All 16 slice loads are independent -> full MLP.
__global__ void __launch_bounds__(256)
weighted_sum_kernel(const float4* __restrict__ data,
                    const unsigned long long* __restrict__ rowmask,
                    const longlong2* __restrict__ colmask2,
                    float* __restrict__ out) {
    int idx = blockIdx.x * 256 + threadIdx.x;     // exactly SITES threads
    int y  = idx / W4;
    int x4 = idx - y * W4;

    unsigned long long rm = rowmask[y];
    longlong2 c01 = colmask2[x4 * 2 + 0];         // colmask[4*x4 + 0,1]
    longlong2 c23 = colmask2[x4 * 2 + 1];         // colmask[4*x4 + 2,3]
    float w0 = (float)__popcll(rm & (unsigned long long)c01.x);
    float w1 = (float)__popcll(rm & (unsigned long long)c01.y);
    float w2 = (float)__popcll(rm & (unsigned long long)c23.x);
    float w3 = (float)__popcll(rm & (unsigned long long)c23.y);

    const float4* p = data + idx;
    float4 v[TT];
#pragma unroll
    for (int t = 0; t < TT; ++t)
        v[t] = p[t * SLICE4];                     // 16 independent dwordx4

    float a0 = 0.f, a1 = 0.f, a2 = 0.f, a3 = 0.f;
#pragma unroll
    for (int t = 0; t < TT; t += 4) {
        a0 += v[t + 0].x * w0 + v[t + 0].y * w1 + v[t + 0].z * w2 + v[t + 0].w * w3;
        a1 += v[t + 1].x * w0 + v[t + 1].y * w1 + v[t + 1].z * w2 + v[t + 1].w * w3;
        a2 += v[t + 2].x * w0 + v[t + 2].y * w1 + v[t + 2].z * w2 + v[t + 2].w * w3;
        a3 += v[t + 3].x * w0 + v[t + 3].y * w1 + v[t + 3].z * w2 + v[t + 3].w * w3;
    }
    float acc = (a0 + a1) + (a2 + a3);

    // 64-lane wave shuffle reduction
#pragma unroll
    for (int off = 32; off > 0; off >>= 1)
        acc += __shfl_down(acc, off, 64);

    __shared__ float wsum[4];
    int lane = threadIdx.x & 63;
    int wid  = threadIdx.x >> 6;
    if (lane == 0) wsum[wid] = acc;
    __syncthreads();
    if (threadIdx.x == 0) {
        float s = (wsum[0] + wsum[1]) + (wsum[2] + wsum[3]);
        atomicAdd(out, s);
    }
}

extern "C" void kernel_launch(void* const* d_in, const int* in_sizes, int n_in,
                              void* d_out, int out_size, void* d_ws, size_t ws_size,
                              hipStream_t stream) {
    const float* data = (const float*)d_in[0];        // (T,H,W) float32
    const int* boxes  = (const int*)d_in[1];          // (N,4) int32
    float* out = (float*)d_out;                       // scalar

    // Workspace: rowmask[HH] u64, colmask[WW] u64 (colmask 16B-aligned:
    // rowmask is at ws base which is 256B-aligned; HH*8 = 10240 keeps it).
    unsigned long long* rowmask = (unsigned long long*)d_ws;
    unsigned long long* colmask = rowmask + HH;

    build_masks_kernel<<<1, 256, 0, stream>>>(boxes, rowmask, colmask, out);
    weighted_sum_kernel<<<SITES / 256, 256, 0, stream>>>(
        (const float4*)data, rowmask, (const longlong2*)colmask, out);
}

// Round 4
// 201.728 us; speedup vs baseline: 1.1359x; 1.0056x over previous
//
#include <hip/hip_runtime.h>

// Problem constants: T=16, H=1280, W=1280, N=64 boxes.
#define TT 16
#define HH 1280
#define WW 1280
#define NBOX 64
#define W4 (WW / 4)            // 320 float4 per row
#define SITES (HH * W4)        // 409600 (y, x4) sites
#define SLICE4 SITES           // float4 per T-slice

// K1: build row/col membership bitmasks (one bit per box); zero d_out.
// boxes[b] = (x1, y1, x2, y2), half-open [lo, hi).
__global__ void build_masks_kernel(const int* __restrict__ boxes,
                                   unsigned long long* __restrict__ rowmask,
                                   unsigned long long* __restrict__ colmask,
                                   float* __restrict__ out) {
    __shared__ int bx1[NBOX], by1[NBOX], bx2[NBOX], by2[NBOX];
    int tid = threadIdx.x;
    if (tid < NBOX) {
        bx1[tid] = boxes[tid * 4 + 0];
        by1[tid] = boxes[tid * 4 + 1];
        bx2[tid] = boxes[tid * 4 + 2];
        by2[tid] = boxes[tid * 4 + 3];
    }
    if (tid == 0) out[0] = 0.0f;
    __syncthreads();
    for (int i = tid; i < HH; i += blockDim.x) {   // H == W
        unsigned long long rm = 0ull, cm = 0ull;
#pragma unroll
        for (int b = 0; b < NBOX; ++b) {
            if (by1[b] <= i && i < by2[b]) rm |= (1ull << b);
            if (bx1[b] <= i && i < bx2[b]) cm |= (1ull << b);
        }
        rowmask[i] = rm;
        colmask[i] = cm;
    }
}

// K2: one thread per (y, x4) site, all T=16 slices, loads issued in two
// batches of 8 to keep VGPR < 64 so all ~6.25 blocks/CU are co-resident in
// ONE generation (launch_bounds(256,8) -> 8 blocks/CU cap).
// // launch_bounds 2nd arg is waves/EU: 8 waves/EU * 4 EU / 4 waves-per-block
// // = 8 blocks/CU, which caps VGPR at 64 and avoids a second block generation.
__global__ void __launch_bounds__(256, 8)
weighted_sum_kernel(const float4* __restrict__ data,
                    const unsigned long long* __restrict__ rowmask,
                    const longlong2* __restrict__ colmask2,
                    float* __restrict__ out) {
    int idx = blockIdx.x * 256 + threadIdx.x;     // exactly SITES threads
    int y  = idx / W4;
    int x4 = idx - y * W4;

    unsigned long long rm = rowmask[y];
    longlong2 c01 = colmask2[x4 * 2 + 0];         // colmask[4*x4 + 0,1]
    longlong2 c23 = colmask2[x4 * 2 + 1];         // colmask[4*x4 + 2,3]
    float w0 = (float)__popcll(rm & (unsigned long long)c01.x);
    float w1 = (float)__popcll(rm & (unsigned long long)c01.y);
    float w2 = (float)__popcll(rm & (unsigned long long)c23.x);
    float w3 = (float)__popcll(rm & (unsigned long long)c23.y);

    const float4* p = data + idx;
    float a0 = 0.f, a1 = 0.f, a2 = 0.f, a3 = 0.f;
    // Two batches of 8 in-flight loads; outer loop deliberately NOT unrolled
    // so only 8 float4 (32 VGPRs) are live at once.
    for (int half = 0; half < 2; ++half) {
        float4 v[8];
#pragma unroll
        for (int t = 0; t < 8; ++t)
            v[t] = p[(half * 8 + t) * SLICE4];    // 8 independent dwordx4
#pragma unroll
        for (int t = 0; t < 8; t += 4) {
            a0 += v[t + 0].x * w0 + v[t + 0].y * w1 + v[t + 0].z * w2 + v[t + 0].w * w3;
            a1 += v[t + 1].x * w0 + v[t + 1].y * w1 + v[t + 1].z * w2 + v[t + 1].w * w3;
            a2 += v[t + 2].x * w0 + v[t + 2].y * w1 + v[t + 2].z * w2 + v[t + 2].w * w3;
            a3 += v[t + 3].x * w0 + v[t + 3].y * w1 + v[t + 3].z * w2 + v[t + 3].w * w3;
        }
    }
    float acc = (a0 + a1) + (a2 + a3);

    // 64-lane wave shuffle reduction
#pragma unroll
    for (int off = 32; off > 0; off >>= 1)
        acc += __shfl_down(acc, off, 64);

    __shared__ float wsum[4];
    int lane = threadIdx.x & 63;
    int wid  = threadIdx.x >> 6;
    if (lane == 0) wsum[wid] = acc;
    __syncthreads();
    if (threadIdx.x == 0) {
        float s = (wsum[0] + wsum[1]) + (wsum[2] + wsum[3]);
        atomicAdd(out, s);
    }
}

extern "C" void kernel_launch(void* const* d_in, const int* in_sizes, int n_in,
                              void* d_out, int out_size, void* d_ws, size_t ws_size,
                              hipStream_t stream) {
    const float* data = (const float*)d_in[0];        // (T,H,W) float32
    const int* boxes  = (const int*)d_in[1];          // (N,4) int32
    float* out = (float*)d_out;                       // scalar

    // Workspace: rowmask[HH] u64, colmask[WW] u64 (colmask stays 16B-aligned:
    // ws base is 256B-aligned and HH*8 = 10240).
    unsigned long long* rowmask = (unsigned long long*)d_ws;
    unsigned long long* colmask = rowmask + HH;

    build_masks_kernel<<<1, 256, 0, stream>>>(boxes, rowmask, colmask, out);
    weighted_sum_kernel<<<SITES / 256, 256, 0, stream>>>(
        (const float4*)data, rowmask, (const longlong2*)colmask, out);
}

// Round 5
// 163.158 us; speedup vs baseline: 1.4044x; 1.2364x over previous
//
#include <hip/hip_runtime.h>

// Problem constants: T=16, H=1280, W=1280, N=64 boxes.
#define TT 16
#define HH 1280
#define WW 1280
#define NBOX 64
#define W4 (WW / 4)            // 320 float4 per row
#define SLICE4 (HH * W4)       // float4 per T-slice
#define TILE_Y 16              // rows per block
#define TILE_X 16              // float4-sites per block (= 64 columns)
#define GRID_X (W4 / TILE_X)   // 20
#define GRID_Y (HH / TILE_Y)   // 80

// Single fused kernel. Each block owns a TILE_Y x TILE_X tile of (y, x4)
// sites across all T=16 slices. Box masks for the tile's 16 rows and 64
// columns are built in LDS by the first 80 threads (one mask each, 64 box
// tests) -- this replaces the former serial 1-block build_masks dispatch.
// weight(y,x) = popcount(rowmask[y] & colmask[x]); sum += w * data[t,y,x].
// __launch_bounds__(256,7): 7 waves/EU -> VGPR<=73 -> all 25 waves/CU of the
// 1600-block grid co-resident in one generation (6.25 blocks/CU needed).
__global__ void __launch_bounds__(256, 7)
fused_boxsum_kernel(const float4* __restrict__ data,
                    const int* __restrict__ boxes,
                    float* __restrict__ out) {
    __shared__ int bx1[NBOX], by1[NBOX], bx2[NBOX], by2[NBOX];
    __shared__ unsigned long long rowm[TILE_Y];        // per-tile row masks
    __shared__ unsigned long long colm[TILE_X * 4];    // per-tile col masks
    __shared__ float wsum[4];

    const int tid = threadIdx.x;
    const int bid = blockIdx.x;                 // 0..1599
    const int ty_tile = bid / GRID_X;           // 0..79
    const int tx_tile = bid - ty_tile * GRID_X; // 0..19

    // Stage boxes into LDS (broadcast-friendly for the mask build).
    if (tid < NBOX) {
        int4 b = ((const int4*)boxes)[tid];     // (x1, y1, x2, y2)
        bx1[tid] = b.x; by1[tid] = b.y; bx2[tid] = b.z; by2[tid] = b.w;
    }
    __syncthreads();

    // Build the tile's masks: threads 0..15 -> rowmask, 16..79 -> colmask.
    if (tid < TILE_Y) {
        int y = ty_tile * TILE_Y + tid;
        unsigned long long m = 0ull;
#pragma unroll
        for (int b = 0; b < NBOX; ++b)
            if (by1[b] <= y && y < by2[b]) m |= (1ull << b);
        rowm[tid] = m;
    } else if (tid < TILE_Y + TILE_X * 4) {
        int cx = tid - TILE_Y;                  // 0..63
        int x = tx_tile * (TILE_X * 4) + cx;
        unsigned long long m = 0ull;
#pragma unroll
        for (int b = 0; b < NBOX; ++b)
            if (bx1[b] <= x && x < bx2[b]) m |= (1ull << b);
        colm[cx] = m;
    }
    __syncthreads();

    // Site assignment: sx = site within tile (fast-varying for coalescing),
    // row = row within tile. A wave covers 4 rows x 16 sites: 4 x 256B
    // contiguous segments at 5120B stride -> fully coalesced.
    const int sx  = tid & (TILE_X - 1);         // 0..15
    const int row = tid >> 4;                   // 0..15
    const int y  = ty_tile * TILE_Y + row;
    const int x4 = tx_tile * TILE_X + sx;

    unsigned long long rm = rowm[row];
    float w0 = (float)__popcll(rm & colm[sx * 4 + 0]);
    float w1 = (float)__popcll(rm & colm[sx * 4 + 1]);
    float w2 = (float)__popcll(rm & colm[sx * 4 + 2]);
    float w3 = (float)__popcll(rm & colm[sx * 4 + 3]);

    const float4* p = data + y * W4 + x4;
    float a0 = 0.f, a1 = 0.f, a2 = 0.f, a3 = 0.f;
    // Two batches of 8 in-flight dwordx4 (32 data VGPRs live) to stay under
    // the 73-VGPR budget of (256,7).
    for (int half = 0; half < 2; ++half) {
        float4 v[8];
#pragma unroll
        for (int t = 0; t < 8; ++t)
            v[t] = p[(half * 8 + t) * SLICE4];
#pragma unroll
        for (int t = 0; t < 8; t += 4) {
            a0 += v[t + 0].x * w0 + v[t + 0].y * w1 + v[t + 0].z * w2 + v[t + 0].w * w3;
            a1 += v[t + 1].x * w0 + v[t + 1].y * w1 + v[t + 1].z * w2 + v[t + 1].w * w3;
            a2 += v[t + 2].x * w0 + v[t + 2].y * w1 + v[t + 2].z * w2 + v[t + 2].w * w3;
            a3 += v[t + 3].x * w0 + v[t + 3].y * w1 + v[t + 3].z * w2 + v[t + 3].w * w3;
        }
    }
    float acc = (a0 + a1) + (a2 + a3);

    // 64-lane wave shuffle reduction -> LDS -> one atomic per block.
#pragma unroll
    for (int off = 32; off > 0; off >>= 1)
        acc += __shfl_down(acc, off, 64);

    int lane = tid & 63;
    int wid  = tid >> 6;
    if (lane == 0) wsum[wid] = acc;
    __syncthreads();
    if (tid == 0) {
        float s = (wsum[0] + wsum[1]) + (wsum[2] + wsum[3]);
        atomicAdd(out, s);
    }
}

extern "C" void kernel_launch(void* const* d_in, const int* in_sizes, int n_in,
                              void* d_out, int out_size, void* d_ws, size_t ws_size,
                              hipStream_t stream) {
    const float* data = (const float*)d_in[0];        // (T,H,W) float32
    const int* boxes  = (const int*)d_in[1];          // (N,4) int32
    float* out = (float*)d_out;                       // scalar (poisoned 0xAA)

    // Zero the accumulator (capturable async memset; harness poisons d_out).
    hipMemsetAsync(out, 0, sizeof(float), stream);

    fused_boxsum_kernel<<<GRID_X * GRID_Y, 256, 0, stream>>>(
        (const float4*)data, boxes, out);
}

// Round 6
// 161.530 us; speedup vs baseline: 1.4186x; 1.0101x over previous
//
#include <hip/hip_runtime.h>

// Problem constants: T=16, H=1280, W=1280, N=64 boxes.
#define TT 16
#define HH 1280
#define WW 1280
#define NBOX 64
#define W4 (WW / 4)            // 320 float4 per row
#define SLICE4 (HH * W4)       // float4 per T-slice
#define TILE_Y 16              // rows per block
#define TILE_X 16              // float4-sites per block (= 64 columns)
#define GRID_X (W4 / TILE_X)   // 20
#define GRID_Y (HH / TILE_Y)   // 80

// Fused kernel, one dispatch. Each block owns a TILE_Y x TILE_X tile of
// (y, x4) sites across all T=16 slices; per-tile box masks built in LDS.
// weight(y,x) = popcount(rowmask[y] & colmask[x]); sum += w * data[t,y,x].
//
// KEY (R5 post-mortem): the kernel is memory-LATENCY bound. All 16 slice
// loads must be independently in flight (64 data VGPRs). launch_bounds(256,5)
// allows ~102 VGPRs -- enough for v[16] + addressing without spill. Do NOT
// batch/roll the load loop: R5's rolled version compiled to VGPR=32 serial
// chains and ran 66 us.
__global__ void __launch_bounds__(256, 5)
fused_boxsum_kernel(const float4* __restrict__ data,
                    const int* __restrict__ boxes,
                    float* __restrict__ out) {
    __shared__ int bx1[NBOX], by1[NBOX], bx2[NBOX], by2[NBOX];
    __shared__ unsigned long long rowm[TILE_Y];        // per-tile row masks
    __shared__ unsigned long long colm[TILE_X * 4];    // per-tile col masks
    __shared__ float wsum[4];

    const int tid = threadIdx.x;
    const int bid = blockIdx.x;                 // 0..1599
    const int ty_tile = bid / GRID_X;           // 0..79
    const int tx_tile = bid - ty_tile * GRID_X; // 0..19

    if (tid < NBOX) {
        int4 b = ((const int4*)boxes)[tid];     // (x1, y1, x2, y2)
        bx1[tid] = b.x; by1[tid] = b.y; bx2[tid] = b.z; by2[tid] = b.w;
    }
    __syncthreads();

    // Threads 0..15 build row masks; 16..79 build col masks.
    if (tid < TILE_Y) {
        int y = ty_tile * TILE_Y + tid;
        unsigned long long m = 0ull;
#pragma unroll
        for (int b = 0; b < NBOX; ++b)
            if (by1[b] <= y && y < by2[b]) m |= (1ull << b);
        rowm[tid] = m;
    } else if (tid < TILE_Y + TILE_X * 4) {
        int cx = tid - TILE_Y;                  // 0..63
        int x = tx_tile * (TILE_X * 4) + cx;
        unsigned long long m = 0ull;
#pragma unroll
        for (int b = 0; b < NBOX; ++b)
            if (bx1[b] <= x && x < bx2[b]) m |= (1ull << b);
        colm[cx] = m;
    }
    __syncthreads();

    // Wave covers 4 rows x 16 sites: 4 contiguous 256B segments -> coalesced.
    const int sx  = tid & (TILE_X - 1);         // 0..15
    const int row = tid >> 4;                   // 0..15
    const int y  = ty_tile * TILE_Y + row;
    const int x4 = tx_tile * TILE_X + sx;

    unsigned long long rm = rowm[row];
    float w0 = (float)__popcll(rm & colm[sx * 4 + 0]);
    float w1 = (float)__popcll(rm & colm[sx * 4 + 1]);
    float w2 = (float)__popcll(rm & colm[sx * 4 + 2]);
    float w3 = (float)__popcll(rm & colm[sx * 4 + 3]);

    // All 16 slice loads issued back-to-back, fully independent (max MLP).
    const float4* p = data + y * W4 + x4;
    float4 v[TT];
#pragma unroll
    for (int t = 0; t < TT; ++t)
        v[t] = p[t * SLICE4];

    float a0 = 0.f, a1 = 0.f, a2 = 0.f, a3 = 0.f;
#pragma unroll
    for (int t = 0; t < TT; t += 4) {
        a0 += v[t + 0].x * w0 + v[t + 0].y * w1 + v[t + 0].z * w2 + v[t + 0].w * w3;
        a1 += v[t + 1].x * w0 + v[t + 1].y * w1 + v[t + 1].z * w2 + v[t + 1].w * w3;
        a2 += v[t + 2].x * w0 + v[t + 2].y * w1 + v[t + 2].z * w2 + v[t + 2].w * w3;
        a3 += v[t + 3].x * w0 + v[t + 3].y * w1 + v[t + 3].z * w2 + v[t + 3].w * w3;
    }
    float acc = (a0 + a1) + (a2 + a3);

    // 64-lane wave shuffle reduction -> LDS -> one atomic per block.
#pragma unroll
    for (int off = 32; off > 0; off >>= 1)
        acc += __shfl_down(acc, off, 64);

    int lane = tid & 63;
    int wid  = tid >> 6;
    if (lane == 0) wsum[wid] = acc;
    __syncthreads();
    if (tid == 0) {
        float s = (wsum[0] + wsum[1]) + (wsum[2] + wsum[3]);
        atomicAdd(out, s);
    }
}

extern "C" void kernel_launch(void* const* d_in, const int* in_sizes, int n_in,
                              void* d_out, int out_size, void* d_ws, size_t ws_size,
                              hipStream_t stream) {
    const float* data = (const float*)d_in[0];        // (T,H,W) float32
    const int* boxes  = (const int*)d_in[1];          // (N,4) int32
    float* out = (float*)d_out;                       // scalar (poisoned 0xAA)

    // NOTE: deliberately no d_ws use -- touching ws triggers 420 MB re-poison
    // fills in the harness reset path (cost ~60 us/replay, observed R2-R4).
    hipMemsetAsync(out, 0, sizeof(float), stream);

    fused_boxsum_kernel<<<GRID_X * GRID_Y, 256, 0, stream>>>(
        (const float4*)data, boxes, out);
}